// Round 1
// baseline (8110.842 us; speedup 1.0000x reference)
//
#include <hip/hip_runtime.h>
#include <math.h>

// Problem constants
#define LSEQ 1024   // sequence length
#define NB   32     // batch
#define IC   256    // input size
#define HC   256    // hidden size
#define G4   1024   // 4*H (gates)
#define D2   512    // 2*H (bi output)
#define TOPK 3

// d_ws layout (floats unless noted):
//   [0, 33554432)            pre_f  (L,B,4H)
//   [33554432, 67108864)     pre_b  (L,B,4H)
//   then 64*1024 ints        flags
#define PRESZ   ((size_t)LSEQ * NB * G4)
#define FLAGS_BYTE_OFF (2 * PRESZ * sizeof(float))

// d_out layout (floats):
//   [0, 196608)              coo   (B, 2, L*K)
//   [196608, 294912)         vals  (B, L, K)
//   [294912, 17072128)       lstm_out (B, L, 2H)
#define COO_OFF  0
#define VALS_OFF ((size_t)NB * 2 * LSEQ * TOPK)
#define LSTM_OFF (VALS_OFF + (size_t)NB * LSEQ * TOPK)

#define ALIGN_SCALE 0.04419417382415922f  // 1/sqrt(512)

// ---------------------------------------------------------------------------
// Kernel Z: zero the flag counters (ws is re-poisoned 0xAA before every launch)
// ---------------------------------------------------------------------------
__global__ void zero_flags_kernel(int* __restrict__ flags) {
    flags[blockIdx.x * 256 + threadIdx.x] = 0;
}

// ---------------------------------------------------------------------------
// Kernel A: input projection  pre[d][l,b,g] = x[l,b,:]·w_ih[d][g,:] + bias[g]
// GEMM M=32768 (l*B+b), N=1024, K=256; both operands K-contiguous (NT).
// BM=BN=128, BK=16, 256 threads, 8x8 acc/thread. fp32 VALU.
// ---------------------------------------------------------------------------
__global__ __launch_bounds__(256) void proj_kernel(
    const float* __restrict__ x,
    const float* __restrict__ w_f, const float* __restrict__ b_f,
    const float* __restrict__ w_b, const float* __restrict__ b_b,
    float* __restrict__ ws) {
    const int dir = blockIdx.z;
    const float* __restrict__ w    = dir ? w_b : w_f;
    const float* __restrict__ bias = dir ? b_b : b_f;
    float* __restrict__ pre = ws + (size_t)dir * PRESZ;

    const int m0 = blockIdx.x * 128;
    const int n0 = blockIdx.y * 128;
    const int tid = threadIdx.x;
    const int tx = tid & 15, ty = tid >> 4;

    __shared__ __align__(16) float As[16][132];  // k-major, pad->2-way max on reads
    __shared__ __align__(16) float Bs[16][132];

    float acc[8][8];
#pragma unroll
    for (int i = 0; i < 8; ++i)
#pragma unroll
        for (int j = 0; j < 8; ++j) acc[i][j] = 0.f;

    for (int k0 = 0; k0 < IC; k0 += 16) {
#pragma unroll
        for (int r = 0; r < 2; ++r) {
            const int e = r * 256 + tid;       // 0..511
            const int row = e >> 2, kq = e & 3;
            float4 va = *(const float4*)&x[(size_t)(m0 + row) * IC + k0 + kq * 4];
            As[kq * 4 + 0][row] = va.x; As[kq * 4 + 1][row] = va.y;
            As[kq * 4 + 2][row] = va.z; As[kq * 4 + 3][row] = va.w;
            float4 vb = *(const float4*)&w[(size_t)(n0 + row) * IC + k0 + kq * 4];
            Bs[kq * 4 + 0][row] = vb.x; Bs[kq * 4 + 1][row] = vb.y;
            Bs[kq * 4 + 2][row] = vb.z; Bs[kq * 4 + 3][row] = vb.w;
        }
        __syncthreads();
#pragma unroll
        for (int k = 0; k < 16; ++k) {
            float4 a0 = *(const float4*)&As[k][ty * 8];
            float4 a1 = *(const float4*)&As[k][ty * 8 + 4];
            float4 c0 = *(const float4*)&Bs[k][tx * 8];
            float4 c1 = *(const float4*)&Bs[k][tx * 8 + 4];
            float av[8] = {a0.x, a0.y, a0.z, a0.w, a1.x, a1.y, a1.z, a1.w};
            float bv[8] = {c0.x, c0.y, c0.z, c0.w, c1.x, c1.y, c1.z, c1.w};
#pragma unroll
            for (int i = 0; i < 8; ++i)
#pragma unroll
                for (int j = 0; j < 8; ++j)
                    acc[i][j] = fmaf(av[i], bv[j], acc[i][j]);
        }
        __syncthreads();
    }

    float bj[8];
#pragma unroll
    for (int j = 0; j < 8; ++j) bj[j] = bias[n0 + tx * 8 + j];
#pragma unroll
    for (int i = 0; i < 8; ++i) {
        const size_t m = (size_t)(m0 + ty * 8 + i);
        float4 o0, o1;
        o0.x = acc[i][0] + bj[0]; o0.y = acc[i][1] + bj[1];
        o0.z = acc[i][2] + bj[2]; o0.w = acc[i][3] + bj[3];
        o1.x = acc[i][4] + bj[4]; o1.y = acc[i][5] + bj[5];
        o1.z = acc[i][6] + bj[6]; o1.w = acc[i][7] + bj[7];
        *(float4*)&pre[m * G4 + n0 + tx * 8]     = o0;
        *(float4*)&pre[m * G4 + n0 + tx * 8 + 4] = o1;
    }
}

// ---------------------------------------------------------------------------
// Kernel B: bidirectional LSTM recurrence.
// 256 blocks x 512 threads (1 block/CU, residency-safe). chain = (dir,b),
// 4 blocks per chain, each owns 64 hidden units (128 gate cols), weights in
// VGPRs (128/thread). h exchanged via lstm_out region of d_out using
// agent-scope atomics + per-(chain,step) flag counters.
// ---------------------------------------------------------------------------
__global__ __launch_bounds__(512, 2) void lstm_kernel(
    const float* __restrict__ w_hh_f, const float* __restrict__ w_hh_b,
    float* __restrict__ ws, float* __restrict__ out) {
    const int blk   = blockIdx.x;      // 0..255
    const int chain = blk >> 2;        // 0..63
    const int slice = blk & 3;         // 0..3
    const int dir   = chain >> 5;      // 0 fwd, 1 bwd
    const int b     = chain & 31;
    const int j0    = slice * 64;

    const float* __restrict__ whh = dir ? w_hh_b : w_hh_f;
    const float* __restrict__ pre = ws + (size_t)dir * PRESZ;
    int* flags = (int*)((char*)ws + FLAGS_BYTE_OFF) + chain * LSEQ;
    float* __restrict__ outl = out + LSTM_OFF;

    const int tid = threadIdx.x;
    const int cl  = tid >> 1;          // 0..255 local gate-col
    const int kh  = tid & 1;           // k half
    const int g   = cl >> 6;           // gate 0..3 (i,f,g,o)
    const int ul  = cl & 63;           // local unit
    const int colg = g * 256 + j0 + ul;  // global gate row in w_hh

    // Load my 128 weights (k = kh*128 .. +128 of row colg) into registers.
    float wreg[128];
    {
        const float* wrow = whh + (size_t)colg * HC + kh * 128;
#pragma unroll
        for (int i = 0; i < 32; ++i) {
            float4 v = *(const float4*)&wrow[i * 4];
            wreg[i * 4 + 0] = v.x; wreg[i * 4 + 1] = v.y;
            wreg[i * 4 + 2] = v.z; wreg[i * 4 + 3] = v.w;
        }
    }

    __shared__ __align__(16) float h_lds[256];
    __shared__ __align__(16) float cg_lds[256];

    float cstate = 0.f;                 // valid for tid < 64
    if (tid < 256) h_lds[tid] = 0.f;
    __syncthreads();

    for (int s = 0; s < LSEQ; ++s) {
        const int t = dir ? (LSEQ - 1 - s) : s;
        // Issue pre load early; latency hides under spin + h load.
        const float preval = pre[((size_t)t * NB + b) * G4 + colg];

        if (s > 0) {
            if (tid == 0) {
                while (__hip_atomic_load(&flags[s - 1], __ATOMIC_ACQUIRE,
                                         __HIP_MEMORY_SCOPE_AGENT) < 4)
                    __builtin_amdgcn_s_sleep(1);
            }
            __syncthreads();
            if (tid < 256) {
                const int tprev = dir ? (t + 1) : (t - 1);
                h_lds[tid] = __hip_atomic_load(
                    &outl[((size_t)b * LSEQ + tprev) * D2 + dir * HC + tid],
                    __ATOMIC_RELAXED, __HIP_MEMORY_SCOPE_AGENT);
            }
            __syncthreads();
        }

        // 128-MAC dot: my half of h · my weight row (registers, static idx)
        float sacc = 0.f;
#pragma unroll
        for (int kk = 0; kk < 32; ++kk) {
            float4 h4 = *(const float4*)&h_lds[kh * 128 + kk * 4];
            sacc = fmaf(wreg[kk * 4 + 0], h4.x, sacc);
            sacc = fmaf(wreg[kk * 4 + 1], h4.y, sacc);
            sacc = fmaf(wreg[kk * 4 + 2], h4.z, sacc);
            sacc = fmaf(wreg[kk * 4 + 3], h4.w, sacc);
        }
        sacc += __shfl_xor(sacc, 1);
        if (kh == 0) cg_lds[cl] = sacc + preval;
        __syncthreads();

        if (tid < 64) {
            const float xi = cg_lds[tid];
            const float xf = cg_lds[64 + tid];
            const float xg = cg_lds[128 + tid];
            const float xo = cg_lds[192 + tid];
            const float ii = 1.f / (1.f + expf(-xi));
            const float ff = 1.f / (1.f + expf(-xf));
            const float gg = tanhf(xg);
            const float oo = 1.f / (1.f + expf(-xo));
            cstate = ff * cstate + ii * gg;
            const float hh = oo * tanhf(cstate);
            __hip_atomic_store(
                &outl[((size_t)b * LSEQ + t) * D2 + dir * HC + j0 + tid], hh,
                __ATOMIC_RELAXED, __HIP_MEMORY_SCOPE_AGENT);
        }
        __syncthreads();  // drains vmcnt: all h stores complete before flag
        if (tid == 0)
            __hip_atomic_fetch_add(&flags[s], 1, __ATOMIC_RELEASE,
                                   __HIP_MEMORY_SCOPE_AGENT);
    }
}

// ---------------------------------------------------------------------------
// Kernel C: align = lstm_out · lstm_outᵀ / sqrt(2H), fused top-3 per row.
// Block = (batch b, 64-row tile). 16 col-tiles of 64, BK=32, 4x4 acc/thread.
// Top-3 kept strictly-descending with lower-index-first ties (JAX top_k).
// ---------------------------------------------------------------------------
__global__ __launch_bounds__(256) void align_topk_kernel(
    const float* __restrict__ outl, float* __restrict__ coo,
    float* __restrict__ vals) {
    const int b  = blockIdx.x;   // 0..31
    const int rt = blockIdx.y;   // 0..15
    const int r0 = rt * 64;
    const float* __restrict__ base = outl + (size_t)b * LSEQ * D2;

    const int tid = threadIdx.x;
    const int tx = tid & 15, ty = tid >> 4;

    __shared__ __align__(16) float As[32][68];
    __shared__ __align__(16) float Bs[32][68];
    __shared__ __align__(16) float tile[64][65];

    float v0 = -INFINITY, v1 = -INFINITY, v2 = -INFINITY;
    int i0 = 0, i1 = 0, i2 = 0;

    for (int ct = 0; ct < 16; ++ct) {
        const int c0 = ct * 64;
        float acc[4][4];
#pragma unroll
        for (int i = 0; i < 4; ++i)
#pragma unroll
            for (int j = 0; j < 4; ++j) acc[i][j] = 0.f;

        for (int k0 = 0; k0 < D2; k0 += 32) {
#pragma unroll
            for (int r = 0; r < 2; ++r) {
                const int e = r * 256 + tid;     // 0..511
                const int row = e >> 3, kq = e & 7;
                float4 va = *(const float4*)&base[(size_t)(r0 + row) * D2 + k0 + kq * 4];
                As[kq * 4 + 0][row] = va.x; As[kq * 4 + 1][row] = va.y;
                As[kq * 4 + 2][row] = va.z; As[kq * 4 + 3][row] = va.w;
                float4 vb = *(const float4*)&base[(size_t)(c0 + row) * D2 + k0 + kq * 4];
                Bs[kq * 4 + 0][row] = vb.x; Bs[kq * 4 + 1][row] = vb.y;
                Bs[kq * 4 + 2][row] = vb.z; Bs[kq * 4 + 3][row] = vb.w;
            }
            __syncthreads();
#pragma unroll
            for (int k = 0; k < 32; ++k) {
                float4 a = *(const float4*)&As[k][ty * 4];
                float4 c = *(const float4*)&Bs[k][tx * 4];
                float av[4] = {a.x, a.y, a.z, a.w};
                float bv[4] = {c.x, c.y, c.z, c.w};
#pragma unroll
                for (int i = 0; i < 4; ++i)
#pragma unroll
                    for (int j = 0; j < 4; ++j)
                        acc[i][j] = fmaf(av[i], bv[j], acc[i][j]);
            }
            __syncthreads();
        }

#pragma unroll
        for (int i = 0; i < 4; ++i)
#pragma unroll
            for (int j = 0; j < 4; ++j)
                tile[ty * 4 + i][tx * 4 + j] = acc[i][j] * ALIGN_SCALE;
        __syncthreads();

        if (tid < 64) {
            for (int j = 0; j < 64; ++j) {
                const float v = tile[tid][j];
                const int idx = c0 + j;
                if (v > v0) { v2 = v1; i2 = i1; v1 = v0; i1 = i0; v0 = v; i0 = idx; }
                else if (v > v1) { v2 = v1; i2 = i1; v1 = v; i1 = idx; }
                else if (v > v2) { v2 = v; i2 = idx; }
            }
        }
        __syncthreads();
    }

    if (tid < 64) {
        const int l = r0 + tid;
        float* vp = vals + ((size_t)b * LSEQ + l) * TOPK;
        vp[0] = v0; vp[1] = v1; vp[2] = v2;
        // coo (B, 2, L*K): [b][0][:] = idx (as float), [b][1][:] = row
        float* c0p = coo + ((size_t)b * 2 + 0) * (LSEQ * TOPK) + l * TOPK;
        float* c1p = coo + ((size_t)b * 2 + 1) * (LSEQ * TOPK) + l * TOPK;
        c0p[0] = (float)i0; c0p[1] = (float)i1; c0p[2] = (float)i2;
        c1p[0] = (float)l;  c1p[1] = (float)l;  c1p[2] = (float)l;
    }
}

// ---------------------------------------------------------------------------
extern "C" void kernel_launch(void* const* d_in, const int* in_sizes, int n_in,
                              void* d_out, int out_size, void* d_ws, size_t ws_size,
                              hipStream_t stream) {
    const float* x      = (const float*)d_in[0];
    const float* w_ih_f = (const float*)d_in[1];
    const float* w_hh_f = (const float*)d_in[2];
    const float* b_f    = (const float*)d_in[3];
    const float* w_ih_b = (const float*)d_in[4];
    const float* w_hh_b = (const float*)d_in[5];
    const float* b_b    = (const float*)d_in[6];

    float* out = (float*)d_out;
    float* ws  = (float*)d_ws;
    int* flags = (int*)((char*)d_ws + FLAGS_BYTE_OFF);

    // Z: zero flag counters (64 chains x 1024 steps)
    zero_flags_kernel<<<(64 * LSEQ) / 256, 256, 0, stream>>>(flags);

    // A: input projections for both directions
    proj_kernel<<<dim3((LSEQ * NB) / 128, G4 / 128, 2), 256, 0, stream>>>(
        x, w_ih_f, b_f, w_ih_b, b_b, ws);

    // B: recurrence (writes lstm_out region of d_out)
    lstm_kernel<<<256, 512, 0, stream>>>(w_hh_f, w_hh_b, ws, out);

    // C: align + top-3 (writes coo + vals regions of d_out)
    align_topk_kernel<<<dim3(NB, LSEQ / 64), 256, 0, stream>>>(
        out + LSTM_OFF, out + COO_OFF, out + VALS_OFF);
}